// Round 1
// baseline (983.304 us; speedup 1.0000x reference)
//
#include <hip/hip_runtime.h>
#include <hip/hip_bf16.h>
#include <math.h>

#define NN 50000
#define IN_DIM 1024
#define EE 100000
#define NUM_REL 40
#define HEADS 4
#define OUT_D 200
#define HID 800
#define BB 8192
#define SLOT_CAP 16384

__device__ inline void atomicMaxF(float* addr, float v) {
    if (v >= 0.f) atomicMax((int*)addr, __float_as_int(v));
    else atomicMin((unsigned int*)addr, __float_as_uint(v));
}

// ---------------- init ----------------
__global__ void k_init(int* slot_of_node, int* srcslot_of_node, float* segmax,
                       float* denom, int* counters) {
    int i = blockIdx.x * 256 + threadIdx.x;
    if (i < NN) { slot_of_node[i] = -1; srcslot_of_node[i] = -1; }
    if (i < SLOT_CAP * HEADS) { segmax[i] = -3e38f; denom[i] = 0.f; }
    if (i < 2) counters[i] = 0;
}

// refined[slot][c] = bias[c]  (aggregation adds on top)
__global__ void k_refined_init(const float* bias, float* refined) {
    int i = blockIdx.x * 256 + threadIdx.x;
    if (i >= SLOT_CAP * HID) return;
    refined[i] = bias[i % HID];
}

// compact the needed dst/score nodes: src_ids ∪ dst_ids
__global__ void k_build_slots(const int* src_ids, const int* dst_ids,
                              int* slot_of_node, int* counters) {
    int i = blockIdx.x * 256 + threadIdx.x;
    if (i >= 2 * BB) return;
    int n = (i < BB) ? src_ids[i] : dst_ids[i - BB];
    if (slot_of_node[n] == -1) {
        if (atomicCAS(&slot_of_node[n], -1, -2) == -1) {
            int s = atomicAdd(&counters[0], 1);
            slot_of_node[n] = s;
        }
    }
}

// Wa[k][c] = sum_d W[k, h*200+d]*a[h][d]  (c<4: a_src, c>=4: a_dst); prel[r][h]
__global__ void k_wa(const float* W, const float* a_src, const float* a_dst,
                     const float* a_rel, const float* rel_feat,
                     float* Wa, float* prel) {
    int tid = blockIdx.x * 256 + threadIdx.x;
    if (tid < IN_DIM * 8) {
        int k = tid >> 3, c = tid & 7;
        const float* a = (c < 4) ? a_src : a_dst;
        int h = c & 3;
        float s = 0.f;
        for (int d = 0; d < OUT_D; ++d)
            s += W[k * HID + h * OUT_D + d] * a[h * OUT_D + d];
        Wa[k * 8 + c] = s;
    } else if (tid < IN_DIM * 8 + NUM_REL * HEADS) {
        int j = tid - IN_DIM * 8;
        int r = j >> 2, h = j & 3;
        float s = 0.f;
        for (int d = 0; d < OUT_D; ++d)
            s += rel_feat[r * HID + h * OUT_D + d] * a_rel[h * OUT_D + d];
        prel[j] = s;
    }
}

// s_src/s_dst = x @ Wa for all N nodes; one wave per node
__global__ __launch_bounds__(256) void k_sgemm(const float* x, const float* Wa,
                                               float* sS, float* sD) {
    __shared__ float swa[IN_DIM * 9];  // stride 9: conflict-free
    for (int i = threadIdx.x; i < IN_DIM * 8; i += 256)
        swa[(i >> 3) * 9 + (i & 7)] = Wa[i];
    __syncthreads();
    int w = threadIdx.x >> 6, lane = threadIdx.x & 63;
    int n = blockIdx.x * 4 + w;
    if (n >= NN) return;
    float acc[8] = {};
    const float* xr = x + (size_t)n * IN_DIM;
    for (int j = 0; j < 16; ++j) {
        int k = j * 64 + lane;
        float xv = xr[k];
        const float* wr = &swa[k * 9];
#pragma unroll
        for (int c = 0; c < 8; ++c) acc[c] += xv * wr[c];
    }
#pragma unroll
    for (int c = 0; c < 8; ++c)
        for (int off = 32; off; off >>= 1) acc[c] += __shfl_down(acc[c], off, 64);
    if (lane == 0) {
#pragma unroll
        for (int h = 0; h < 4; ++h) {
            sS[n * 4 + h] = acc[h];
            sD[n * 4 + h] = acc[4 + h];
        }
    }
}

// pass 1 over edges: logits + leaky relu, atomicMax segmax, mark needed srcs
__global__ void k_edge1(const int* ei, const int* etype, const int* slot_of_node,
                        int* srcslot_of_node, int* node_of_srcslot, int* counters,
                        const float* sS, const float* sD, const float* prel,
                        float* logit_buf, float* segmax) {
    int e = blockIdx.x * 256 + threadIdx.x;
    if (e >= EE) return;
    int dn = ei[EE + e];
    int slot = slot_of_node[dn];
    if (slot < 0) return;
    int sn = ei[e];
    if (srcslot_of_node[sn] == -1) {
        if (atomicCAS(&srcslot_of_node[sn], -1, -2) == -1) {
            int t = atomicAdd(&counters[1], 1);
            node_of_srcslot[t] = sn;
            srcslot_of_node[sn] = t;
        }
    }
    int r = etype[e];
#pragma unroll
    for (int h = 0; h < 4; ++h) {
        float lg = sS[sn * 4 + h] + sD[dn * 4 + h] + prel[r * 4 + h];
        lg = lg > 0.f ? lg : 0.2f * lg;
        logit_buf[e * 4 + h] = lg;
        atomicMaxF(&segmax[slot * 4 + h], lg);
    }
}

// gathered fp32 GEMM: h_src[t][c] = x[node_of_srcslot[t]] @ W, t < nsrc
#define BM 64
#define BN 64
#define BK 16
__global__ __launch_bounds__(256) void k_hgemm(const float* x, const float* W,
                                               const int* node_of_srcslot,
                                               const int* counters, float* h_src) {
    int nsrc = counters[1];
    int row0 = blockIdx.y * BM;
    if (row0 >= nsrc) return;
    int col0 = blockIdx.x * BN;
    __shared__ float As[BK][BM];
    __shared__ float Bs[BK][BN];
    int t = threadIdx.x;
    int tx = t & 15, ty = t >> 4;
    // A-load mapping: row am (0..63), 4 consecutive k at ak4
    int am = t >> 2, ak4 = (t & 3) * 4;
    int gr_a = row0 + am;
    int node = node_of_srcslot[(gr_a < nsrc) ? gr_a : 0];
    const float* arow = x + (size_t)node * IN_DIM + ak4;
    // B-load mapping: row bk (0..15), 4 consecutive cols at bc4
    int bk = t >> 4, bc4 = (t & 15) * 4;
    int bcol = col0 + bc4;
    bool bvalid = bcol < HID;
    float acc[4][4] = {};
    for (int k0 = 0; k0 < IN_DIM; k0 += BK) {
        float4 av = *(const float4*)(arow + k0);
        As[ak4 + 0][am] = av.x;
        As[ak4 + 1][am] = av.y;
        As[ak4 + 2][am] = av.z;
        As[ak4 + 3][am] = av.w;
        float4 bv = make_float4(0.f, 0.f, 0.f, 0.f);
        if (bvalid) bv = *(const float4*)(W + (size_t)(k0 + bk) * HID + bcol);
        *(float4*)&Bs[bk][bc4] = bv;
        __syncthreads();
#pragma unroll
        for (int kk = 0; kk < BK; ++kk) {
            float af[4], bf[4];
#pragma unroll
            for (int i = 0; i < 4; ++i) af[i] = As[kk][ty * 4 + i];
#pragma unroll
            for (int j = 0; j < 4; ++j) bf[j] = Bs[kk][tx * 4 + j];
#pragma unroll
            for (int i = 0; i < 4; ++i)
#pragma unroll
                for (int j = 0; j < 4; ++j) acc[i][j] += af[i] * bf[j];
        }
        __syncthreads();
    }
#pragma unroll
    for (int i = 0; i < 4; ++i) {
        int gr = row0 + ty * 4 + i;
        if (gr < nsrc) {
            int c = col0 + tx * 4;
            if (c < HID) {
                float4 v = make_float4(acc[i][0], acc[i][1], acc[i][2], acc[i][3]);
                *(float4*)&h_src[(size_t)gr * HID + c] = v;
            }
        }
    }
}

// pass 2: e = exp(logit - segmax), denom += e
__global__ void k_edge2(const int* ei, const int* slot_of_node,
                        float* logit_buf, const float* segmax, float* denom) {
    int e = blockIdx.x * 256 + threadIdx.x;
    if (e >= EE) return;
    int dn = ei[EE + e];
    int slot = slot_of_node[dn];
    if (slot < 0) return;
#pragma unroll
    for (int h = 0; h < 4; ++h) {
        float ex = expf(logit_buf[e * 4 + h] - segmax[slot * 4 + h]);
        logit_buf[e * 4 + h] = ex;
        atomicAdd(&denom[slot * 4 + h], ex);
    }
}

// scatter: refined[slot] += alpha_h * h_src[t]  (one block per edge)
__global__ __launch_bounds__(256) void k_scatter(const int* ei, const int* slot_of_node,
                                                 const int* srcslot_of_node,
                                                 const float* logit_buf, const float* denom,
                                                 const float* h_src, float* refined) {
    int e = blockIdx.x;
    int dn = ei[EE + e];
    int slot = slot_of_node[dn];
    if (slot < 0) return;
    int sn = ei[e];
    int t = srcslot_of_node[sn];
    __shared__ float alpha[4];
    if (threadIdx.x < 4)
        alpha[threadIdx.x] = logit_buf[e * 4 + threadIdx.x] / denom[slot * 4 + threadIdx.x];
    __syncthreads();
    const float* hr = h_src + (size_t)t * HID;
    float* rr = refined + (size_t)slot * HID;
    for (int c = threadIdx.x; c < HID; c += 256) {
        int h = c / OUT_D;
        atomicAdd(&rr[c], alpha[h] * hr[c]);
    }
}

// DistMult scoring: one wave per triple
__global__ __launch_bounds__(256) void k_score(const int* src_ids, const int* rel_ids,
                                               const int* dst_ids, const int* slot_of_node,
                                               const float* rel_emb, const float* refined,
                                               float* out) {
    int gid = blockIdx.x * 256 + threadIdx.x;
    int b = gid >> 6;
    int lane = threadIdx.x & 63;
    if (b >= BB) return;
    int ss = slot_of_node[src_ids[b]];
    int ds = slot_of_node[dst_ids[b]];
    int r = rel_ids[b];
    const float* sv = refined + (size_t)ss * HID;
    const float* dv = refined + (size_t)ds * HID;
    const float* rv = rel_emb + (size_t)r * HID;
    float acc = 0.f;
    for (int c = lane; c < HID; c += 64) acc += sv[c] * rv[c] * dv[c];
    for (int off = 32; off; off >>= 1) acc += __shfl_down(acc, off, 64);
    if (lane == 0) out[b] = acc;
}

extern "C" void kernel_launch(void* const* d_in, const int* in_sizes, int n_in,
                              void* d_out, int out_size, void* d_ws, size_t ws_size,
                              hipStream_t stream) {
    const float* node_emb = (const float*)d_in[0];
    const float* W        = (const float*)d_in[1];
    const float* bias     = (const float*)d_in[2];
    const float* a_src    = (const float*)d_in[3];
    const float* a_dst    = (const float*)d_in[4];
    const float* a_rel    = (const float*)d_in[5];
    const float* rel_feat = (const float*)d_in[6];
    const float* rel_emb  = (const float*)d_in[7];
    const int* edge_index = (const int*)d_in[8];
    const int* edge_type  = (const int*)d_in[9];
    const int* src_ids    = (const int*)d_in[10];
    const int* rel_ids    = (const int*)d_in[11];
    const int* dst_ids    = (const int*)d_in[12];
    float* out = (float*)d_out;

    char* w = (char*)d_ws;
    auto alloc = [&](size_t bytes) -> void* {
        void* p = (void*)w;
        w += (bytes + 255) & ~(size_t)255;
        return p;
    };
    int* slot_of_node    = (int*)alloc((size_t)NN * 4);
    int* srcslot_of_node = (int*)alloc((size_t)NN * 4);
    int* node_of_srcslot = (int*)alloc((size_t)NN * 4);
    int* counters        = (int*)alloc(256);
    float* sS      = (float*)alloc((size_t)NN * 4 * 4);
    float* sD      = (float*)alloc((size_t)NN * 4 * 4);
    float* Wa      = (float*)alloc((size_t)IN_DIM * 8 * 4);
    float* prel    = (float*)alloc((size_t)NUM_REL * 4 * 4);
    float* segmax  = (float*)alloc((size_t)SLOT_CAP * 4 * 4);
    float* denom   = (float*)alloc((size_t)SLOT_CAP * 4 * 4);
    float* logit_buf = (float*)alloc((size_t)EE * 4 * 4);
    float* h_src   = (float*)alloc((size_t)NN * HID * 4);
    float* refined = (float*)alloc((size_t)SLOT_CAP * HID * 4);

    k_init<<<256, 256, 0, stream>>>(slot_of_node, srcslot_of_node, segmax, denom, counters);
    k_refined_init<<<(SLOT_CAP * HID + 255) / 256, 256, 0, stream>>>(bias, refined);
    k_build_slots<<<(2 * BB + 255) / 256, 256, 0, stream>>>(src_ids, dst_ids, slot_of_node, counters);
    k_wa<<<(IN_DIM * 8 + NUM_REL * HEADS + 255) / 256, 256, 0, stream>>>(
        W, a_src, a_dst, a_rel, rel_feat, Wa, prel);
    k_sgemm<<<(NN + 3) / 4, 256, 0, stream>>>(node_emb, Wa, sS, sD);
    k_edge1<<<(EE + 255) / 256, 256, 0, stream>>>(edge_index, edge_type, slot_of_node,
                                                  srcslot_of_node, node_of_srcslot, counters,
                                                  sS, sD, prel, logit_buf, segmax);
    dim3 ggrid((HID + BN - 1) / BN, (NN + BM - 1) / BM);
    k_hgemm<<<ggrid, 256, 0, stream>>>(node_emb, W, node_of_srcslot, counters, h_src);
    k_edge2<<<(EE + 255) / 256, 256, 0, stream>>>(edge_index, slot_of_node, logit_buf, segmax, denom);
    k_scatter<<<EE, 256, 0, stream>>>(edge_index, slot_of_node, srcslot_of_node,
                                      logit_buf, denom, h_src, refined);
    k_score<<<(BB * 64 + 255) / 256, 256, 0, stream>>>(src_ids, rel_ids, dst_ids,
                                                       slot_of_node, rel_emb, refined, out);
}

// Round 2
// 539.752 us; speedup vs baseline: 1.8218x; 1.8218x over previous
//
#include <hip/hip_runtime.h>
#include <hip/hip_bf16.h>
#include <math.h>

#define NN 50000
#define IN_DIM 1024
#define EE 100000
#define NUM_REL 40
#define HEADS 4
#define OUT_D 200
#define HID 800
#define BB 8192
#define SLOT_CAP 16384
#define SRC_CAP 50176   // max nsrc (<=NN) rounded up + tile slack

typedef __attribute__((ext_vector_type(8))) short short8;
typedef __attribute__((ext_vector_type(4))) float f32x4;

__device__ inline unsigned short f2bf(float f) {
    unsigned int u = __float_as_uint(f);
    u += 0x7FFF + ((u >> 16) & 1);
    return (unsigned short)(u >> 16);
}
__device__ inline float bf2f(unsigned short s) {
    return __uint_as_float(((unsigned int)s) << 16);
}

// ---------------- init ----------------
__global__ void k_init(int* slot_of_node, int* srcslot_of_node, int* deg, int* counters) {
    int i = blockIdx.x * 256 + threadIdx.x;
    if (i < NN) { slot_of_node[i] = -1; srcslot_of_node[i] = -1; }
    if (i < SLOT_CAP) deg[i] = 0;
    if (i < 4) counters[i] = 0;
}

// compact the needed dst/score nodes: src_ids ∪ dst_ids
__global__ void k_build_slots(const int* src_ids, const int* dst_ids,
                              int* slot_of_node, int* counters) {
    int i = blockIdx.x * 256 + threadIdx.x;
    if (i >= 2 * BB) return;
    int n = (i < BB) ? src_ids[i] : dst_ids[i - BB];
    if (slot_of_node[n] == -1) {
        if (atomicCAS(&slot_of_node[n], -1, -2) == -1) {
            int s = atomicAdd(&counters[0], 1);
            slot_of_node[n] = s;
        }
    }
}

// Wa[k][c] = sum_d W[k, h*200+d]*a[h][d]  (c<4: a_src, c>=4: a_dst); prel[r][h]
__global__ void k_wa(const float* W, const float* a_src, const float* a_dst,
                     const float* a_rel, const float* rel_feat,
                     float* Wa, float* prel) {
    int tid = blockIdx.x * 256 + threadIdx.x;
    if (tid < IN_DIM * 8) {
        int k = tid >> 3, c = tid & 7;
        const float* a = (c < 4) ? a_src : a_dst;
        int h = c & 3;
        float s = 0.f;
        for (int d = 0; d < OUT_D; ++d)
            s += W[k * HID + h * OUT_D + d] * a[h * OUT_D + d];
        Wa[k * 8 + c] = s;
    } else if (tid < IN_DIM * 8 + NUM_REL * HEADS) {
        int j = tid - IN_DIM * 8;
        int r = j >> 2, h = j & 3;
        float s = 0.f;
        for (int d = 0; d < OUT_D; ++d)
            s += rel_feat[r * HID + h * OUT_D + d] * a_rel[h * OUT_D + d];
        prel[j] = s;
    }
}

// s_src/s_dst = x @ Wa for all N nodes; one wave per node (fp32, exact logits path)
__global__ __launch_bounds__(256) void k_sgemm(const float* x, const float* Wa,
                                               float* sS, float* sD) {
    __shared__ float swa[IN_DIM * 9];  // stride 9: conflict-free
    for (int i = threadIdx.x; i < IN_DIM * 8; i += 256)
        swa[(i >> 3) * 9 + (i & 7)] = Wa[i];
    __syncthreads();
    int w = threadIdx.x >> 6, lane = threadIdx.x & 63;
    int n = blockIdx.x * 4 + w;
    if (n >= NN) return;
    float acc[8] = {};
    const float* xr = x + (size_t)n * IN_DIM;
    for (int j = 0; j < 16; ++j) {
        int k = j * 64 + lane;
        float xv = xr[k];
        const float* wr = &swa[k * 9];
#pragma unroll
        for (int c = 0; c < 8; ++c) acc[c] += xv * wr[c];
    }
#pragma unroll
    for (int c = 0; c < 8; ++c)
        for (int off = 32; off; off >>= 1) acc[c] += __shfl_down(acc[c], off, 64);
    if (lane == 0) {
#pragma unroll
        for (int h = 0; h < 4; ++h) {
            sS[n * 4 + h] = acc[h];
            sD[n * 4 + h] = acc[4 + h];
        }
    }
}

// edge pass: logits + leaky relu, per-slot degree count, src compaction
__global__ void k_edge1(const int* ei, const int* etype, const int* slot_of_node,
                        int* srcslot_of_node, int* node_of_srcslot, int* counters,
                        const float* sS, const float* sD, const float* prel,
                        float* logit_buf, int* deg) {
    int e = blockIdx.x * 256 + threadIdx.x;
    if (e >= EE) return;
    int dn = ei[EE + e];
    int slot = slot_of_node[dn];
    if (slot < 0) return;
    int sn = ei[e];
    if (srcslot_of_node[sn] == -1) {
        if (atomicCAS(&srcslot_of_node[sn], -1, -2) == -1) {
            int t = atomicAdd(&counters[1], 1);
            node_of_srcslot[t] = sn;
            srcslot_of_node[sn] = t;
        }
    }
    int r = etype[e];
#pragma unroll
    for (int h = 0; h < 4; ++h) {
        float lg = sS[sn * 4 + h] + sD[dn * 4 + h] + prel[r * 4 + h];
        lg = lg > 0.f ? lg : 0.2f * lg;
        logit_buf[e * 4 + h] = lg;
    }
    atomicAdd(&deg[slot], 1);
}

// exclusive prefix sum over deg[SLOT_CAP] -> base, cursor (single block)
__global__ __launch_bounds__(256) void k_scan(const int* deg, int* base, int* cursor) {
    __shared__ int pref[257];
    int t = threadIdx.x;
    int s = 0;
    for (int i = 0; i < SLOT_CAP / 256; ++i) s += deg[t * (SLOT_CAP / 256) + i];
    pref[t + 1] = s;
    if (t == 0) pref[0] = 0;
    __syncthreads();
    if (t == 0)
        for (int i = 1; i <= 256; ++i) pref[i] += pref[i - 1];
    __syncthreads();
    int r = pref[t];
    for (int i = 0; i < SLOT_CAP / 256; ++i) {
        int idx = t * (SLOT_CAP / 256) + i;
        base[idx] = r;
        cursor[idx] = r;
        r += deg[idx];
    }
}

// place surviving edges into CSR lists
__global__ void k_place(const int* ei, const int* slot_of_node, const int* srcslot_of_node,
                        int* cursor, int* edge_id, int* tlist) {
    int e = blockIdx.x * 256 + threadIdx.x;
    if (e >= EE) return;
    int dn = ei[EE + e];
    int slot = slot_of_node[dn];
    if (slot < 0) return;
    int pos = atomicAdd(&cursor[slot], 1);
    edge_id[pos] = e;
    tlist[pos] = srcslot_of_node[ei[e]];
}

// gather + cast needed source rows to bf16: xg[t][k] = bf16(x[node_of_srcslot[t]][k])
__global__ void k_gather_cast(const float* x, const int* node_of_srcslot,
                              const int* counters, unsigned short* xg) {
    int gid = blockIdx.x * 256 + threadIdx.x;
    int row = gid >> 7;            // 128 threads per row, 8 elems each
    if (row >= counters[1]) return;
    int j = (gid & 127) * 8;
    int node = node_of_srcslot[row];
    const float* src = x + (size_t)node * IN_DIM + j;
    float4 a = *(const float4*)(src);
    float4 b = *(const float4*)(src + 4);
    unsigned short o[8] = {f2bf(a.x), f2bf(a.y), f2bf(a.z), f2bf(a.w),
                           f2bf(b.x), f2bf(b.y), f2bf(b.z), f2bf(b.w)};
    *(short8*)(xg + (size_t)row * IN_DIM + j) = *(short8*)o;
}

// transpose + cast W[1024][800] -> Wt[896][1024] bf16 (zero-pad cols >= 800)
__global__ __launch_bounds__(256) void k_wt(const float* W, unsigned short* Wt) {
    __shared__ float tile[64][65];
    int k0 = blockIdx.x * 64, c0 = blockIdx.y * 64;
    int t = threadIdx.x;
    {
        int kk = t >> 2, cc = (t & 3) * 16;
        for (int i = 0; i < 16; ++i) {
            int c = c0 + cc + i;
            tile[cc + i][kk] = (c < HID) ? W[(size_t)(k0 + kk) * HID + c] : 0.f;
        }
    }
    __syncthreads();
    {
        int cc = t >> 2, kk = (t & 3) * 16;
        unsigned short o[16];
        for (int i = 0; i < 16; ++i) o[i] = f2bf(tile[cc][kk + i]);
        *(short8*)(Wt + (size_t)(c0 + cc) * IN_DIM + k0 + kk) = *(short8*)o;
        *(short8*)(Wt + (size_t)(c0 + cc) * IN_DIM + k0 + kk + 8) = *(short8*)(o + 8);
    }
}

// MFMA bf16 GEMM: h_src[t][c] = xg[t] . Wt[c], t < nsrc. 128x128 tile, 4 waves.
#define GBM 128
#define GBN 128
#define GBK 32
#define LSTR 40  // LDS row stride in bf16 elems (pad 32->40)
__global__ __launch_bounds__(256) void k_hgemm(const unsigned short* xg, const unsigned short* Wt,
                                               const int* counters, unsigned short* h_src) {
    int nsrc = counters[1];
    int row0 = blockIdx.y * GBM;
    if (row0 >= nsrc) return;
    int col0 = blockIdx.x * GBN;
    __shared__ unsigned short As[GBM * LSTR];
    __shared__ unsigned short Bs[GBN * LSTR];
    int t = threadIdx.x;
    int srow = t >> 1, soff = (t & 1) * 16;
    const unsigned short* ag = xg + (size_t)(row0 + srow) * IN_DIM + soff;
    const unsigned short* bg = Wt + (size_t)(col0 + srow) * IN_DIM + soff;
    int w = t >> 6, lane = t & 63;
    int wr = (w >> 1) * 64, wc = (w & 1) * 64;
    int fm = lane & 15, fq = lane >> 4;
    f32x4 acc[4][4] = {};
    for (int k0 = 0; k0 < IN_DIM; k0 += GBK) {
        short8 av0 = *(const short8*)(ag + k0);
        short8 av1 = *(const short8*)(ag + k0 + 8);
        short8 bv0 = *(const short8*)(bg + k0);
        short8 bv1 = *(const short8*)(bg + k0 + 8);
        __syncthreads();
        *(short8*)&As[srow * LSTR + soff] = av0;
        *(short8*)&As[srow * LSTR + soff + 8] = av1;
        *(short8*)&Bs[srow * LSTR + soff] = bv0;
        *(short8*)&Bs[srow * LSTR + soff + 8] = bv1;
        __syncthreads();
        short8 af[4], bf[4];
#pragma unroll
        for (int i = 0; i < 4; ++i)
            af[i] = *(const short8*)&As[(wr + i * 16 + fm) * LSTR + fq * 8];
#pragma unroll
        for (int j = 0; j < 4; ++j)
            bf[j] = *(const short8*)&Bs[(wc + j * 16 + fm) * LSTR + fq * 8];
#pragma unroll
        for (int i = 0; i < 4; ++i)
#pragma unroll
            for (int j = 0; j < 4; ++j)
                acc[i][j] = __builtin_amdgcn_mfma_f32_16x16x32_bf16(af[i], bf[j], acc[i][j], 0, 0, 0);
    }
#pragma unroll
    for (int i = 0; i < 4; ++i) {
#pragma unroll
        for (int j = 0; j < 4; ++j) {
            int gcol = col0 + wc + j * 16 + fm;
            if (gcol >= HID) continue;
#pragma unroll
            for (int r = 0; r < 4; ++r) {
                int grow = row0 + wr + i * 16 + fq * 4 + r;
                if (grow < nsrc)
                    h_src[(size_t)grow * HID + gcol] = f2bf(acc[i][j][r]);
            }
        }
    }
}

// per-dst-slot softmax + aggregate (no atomics): one block per slot
__global__ __launch_bounds__(256) void k_aggregate(const int* counters, const int* base,
                                                   const int* deg, const int* edge_id,
                                                   const int* tlist, const float* logit_buf,
                                                   const unsigned short* h_src, const float* bias,
                                                   float* refined) {
    int b = blockIdx.x;
    if (b >= counters[0]) return;
    int beg = base[b], d = deg[b];
    __shared__ float m4[4], den4[4];
    __shared__ float alpha[64][4];
    __shared__ int tsl[64];
    int t = threadIdx.x;
    if (t < 4) {
        float m = -3e38f;
        for (int j = 0; j < d; ++j)
            m = fmaxf(m, logit_buf[edge_id[beg + j] * 4 + t]);
        float s = 0.f;
        for (int j = 0; j < d; ++j)
            s += expf(logit_buf[edge_id[beg + j] * 4 + t] - m);
        m4[t] = m;
        den4[t] = s;
    }
    __syncthreads();
    int h0 = t / 200, h1 = (t + 256) / 200, h2 = (t + 512) / 200;
    float acc0 = 0.f, acc1 = 0.f, acc2 = 0.f, acc3 = 0.f;
    for (int j0 = 0; j0 < d; j0 += 64) {
        int nc = min(64, d - j0);
        if (t < nc * 4) {
            int j = t >> 2, h = t & 3;
            int e = edge_id[beg + j0 + j];
            alpha[j][h] = expf(logit_buf[e * 4 + h] - m4[h]) / den4[h];
            if (h == 0) tsl[j] = tlist[beg + j0 + j];
        }
        __syncthreads();
        for (int j = 0; j < nc; ++j) {
            const unsigned short* hr = h_src + (size_t)tsl[j] * HID;
            acc0 += alpha[j][h0] * bf2f(hr[t]);
            acc1 += alpha[j][h1] * bf2f(hr[t + 256]);
            acc2 += alpha[j][h2] * bf2f(hr[t + 512]);
            if (t < 32) acc3 += alpha[j][3] * bf2f(hr[768 + t]);
        }
        __syncthreads();
    }
    float* rr = refined + (size_t)b * HID;
    rr[t] = acc0 + bias[t];
    rr[t + 256] = acc1 + bias[t + 256];
    rr[t + 512] = acc2 + bias[t + 512];
    if (t < 32) rr[768 + t] = acc3 + bias[768 + t];
}

// DistMult scoring: one wave per triple
__global__ __launch_bounds__(256) void k_score(const int* src_ids, const int* rel_ids,
                                               const int* dst_ids, const int* slot_of_node,
                                               const float* rel_emb, const float* refined,
                                               float* out) {
    int gid = blockIdx.x * 256 + threadIdx.x;
    int b = gid >> 6;
    int lane = threadIdx.x & 63;
    if (b >= BB) return;
    int ss = slot_of_node[src_ids[b]];
    int ds = slot_of_node[dst_ids[b]];
    int r = rel_ids[b];
    const float* sv = refined + (size_t)ss * HID;
    const float* dv = refined + (size_t)ds * HID;
    const float* rv = rel_emb + (size_t)r * HID;
    float acc = 0.f;
    for (int c = lane; c < HID; c += 64) acc += sv[c] * rv[c] * dv[c];
    for (int off = 32; off; off >>= 1) acc += __shfl_down(acc, off, 64);
    if (lane == 0) out[b] = acc;
}

extern "C" void kernel_launch(void* const* d_in, const int* in_sizes, int n_in,
                              void* d_out, int out_size, void* d_ws, size_t ws_size,
                              hipStream_t stream) {
    const float* node_emb = (const float*)d_in[0];
    const float* W        = (const float*)d_in[1];
    const float* bias     = (const float*)d_in[2];
    const float* a_src    = (const float*)d_in[3];
    const float* a_dst    = (const float*)d_in[4];
    const float* a_rel    = (const float*)d_in[5];
    const float* rel_feat = (const float*)d_in[6];
    const float* rel_emb  = (const float*)d_in[7];
    const int* edge_index = (const int*)d_in[8];
    const int* edge_type  = (const int*)d_in[9];
    const int* src_ids    = (const int*)d_in[10];
    const int* rel_ids    = (const int*)d_in[11];
    const int* dst_ids    = (const int*)d_in[12];
    float* out = (float*)d_out;

    char* w = (char*)d_ws;
    auto alloc = [&](size_t bytes) -> void* {
        void* p = (void*)w;
        w += (bytes + 255) & ~(size_t)255;
        return p;
    };
    int* slot_of_node    = (int*)alloc((size_t)NN * 4);
    int* srcslot_of_node = (int*)alloc((size_t)NN * 4);
    int* node_of_srcslot = (int*)alloc((size_t)NN * 4);
    int* counters        = (int*)alloc(256);
    int* deg             = (int*)alloc((size_t)SLOT_CAP * 4);
    int* base            = (int*)alloc((size_t)SLOT_CAP * 4);
    int* cursor          = (int*)alloc((size_t)SLOT_CAP * 4);
    int* edge_id         = (int*)alloc((size_t)EE * 4);
    int* tlist           = (int*)alloc((size_t)EE * 4);
    float* sS        = (float*)alloc((size_t)NN * 4 * 4);
    float* sD        = (float*)alloc((size_t)NN * 4 * 4);
    float* Wa        = (float*)alloc((size_t)IN_DIM * 8 * 4);
    float* prel      = (float*)alloc((size_t)NUM_REL * 4 * 4);
    float* logit_buf = (float*)alloc((size_t)EE * 4 * 4);
    unsigned short* xg    = (unsigned short*)alloc((size_t)SRC_CAP * IN_DIM * 2);
    unsigned short* Wt    = (unsigned short*)alloc((size_t)896 * IN_DIM * 2);
    unsigned short* h_src = (unsigned short*)alloc((size_t)NN * HID * 2);
    float* refined = (float*)alloc((size_t)SLOT_CAP * HID * 4);

    k_init<<<256, 256, 0, stream>>>(slot_of_node, srcslot_of_node, deg, counters);
    k_build_slots<<<(2 * BB + 255) / 256, 256, 0, stream>>>(src_ids, dst_ids, slot_of_node, counters);
    k_wa<<<(IN_DIM * 8 + NUM_REL * HEADS + 255) / 256, 256, 0, stream>>>(
        W, a_src, a_dst, a_rel, rel_feat, Wa, prel);
    k_sgemm<<<(NN + 3) / 4, 256, 0, stream>>>(node_emb, Wa, sS, sD);
    k_edge1<<<(EE + 255) / 256, 256, 0, stream>>>(edge_index, edge_type, slot_of_node,
                                                  srcslot_of_node, node_of_srcslot, counters,
                                                  sS, sD, prel, logit_buf, deg);
    k_scan<<<1, 256, 0, stream>>>(deg, base, cursor);
    k_place<<<(EE + 255) / 256, 256, 0, stream>>>(edge_index, slot_of_node, srcslot_of_node,
                                                  cursor, edge_id, tlist);
    k_gather_cast<<<(NN * 128 + 255) / 256, 256, 0, stream>>>(node_emb, node_of_srcslot,
                                                              counters, xg);
    k_wt<<<dim3(IN_DIM / 64, 896 / 64), 256, 0, stream>>>(W, Wt);
    dim3 ggrid((HID + GBN - 1) / GBN, (NN + GBM - 1) / GBM);
    k_hgemm<<<ggrid, 256, 0, stream>>>(xg, Wt, counters, h_src);
    k_aggregate<<<SLOT_CAP, 256, 0, stream>>>(counters, base, deg, edge_id, tlist,
                                              logit_buf, h_src, bias, refined);
    k_score<<<(BB * 64 + 255) / 256, 256, 0, stream>>>(src_ids, rel_ids, dst_ids,
                                                       slot_of_node, rel_emb, refined, out);
}